// Round 8
// baseline (231.732 us; speedup 1.0000x reference)
//
#include <hip/hip_runtime.h>
#include <hip/hip_bf16.h>
#include <string.h>

#define L 4096
#define D 256
#define H 8
#define DH 32

typedef __attribute__((ext_vector_type(8))) short bf16x8;
typedef __attribute__((ext_vector_type(4))) float f32x4;

#define LOG2E 1.4426950408889634f
#define RS (0.17677669529663688f * LOG2E)   // 1/sqrt(DH) * log2(e), folded into Q

__device__ __forceinline__ ushort f2bf(float f) {
    union { float f; unsigned int i; } v; v.f = f;
    unsigned int x = v.i;
    return (ushort)((x + 0x7fffu + ((x >> 16) & 1u)) >> 16);   // RNE
}
__device__ __forceinline__ bf16x8 cvt8(const float* p) {
    float4 a = *(const float4*)p;
    float4 b = *(const float4*)(p + 4);
    bf16x8 r;
    r[0] = (short)f2bf(a.x); r[1] = (short)f2bf(a.y);
    r[2] = (short)f2bf(a.z); r[3] = (short)f2bf(a.w);
    r[4] = (short)f2bf(b.x); r[5] = (short)f2bf(b.y);
    r[6] = (short)f2bf(b.z); r[7] = (short)f2bf(b.w);
    return r;
}
// pack two fp32 -> bf16x2 dword (low = a, high = b); native v_cvt_pk_bf16_f32 on gfx950
__device__ __forceinline__ unsigned int pkbf(float a, float b) {
    float2 t; t.x = a; t.y = b;
    __hip_bfloat162 r = __float22bfloat162_rn(t);
    unsigned int u; memcpy(&u, &r, 4);
    return u;
}

// sigma: logical key u (0..63) -> K storage row within its 64-block.
__device__ __forceinline__ int ksig(int u) {
    return 32 * (u >> 5) + 16 * ((u >> 2) & 1) + 4 * ((u >> 3) & 3) + (u & 3);
}

// ---------------- Kernel 0: prepack ----------------
// b<512: mask rows 8b..8b+8 -> sigma-permuted e<<4 byte stream
// [512,1024): x->bf16 ; [1024,1120): in_w ; [1120,1152): out_w
__global__ __launch_bounds__(256) void pack_kernel(
        const int* __restrict__ mask, const float* __restrict__ x,
        const float* __restrict__ wi, const float* __restrict__ wo,
        unsigned int* __restrict__ m2, ushort* __restrict__ xb,
        ushort* __restrict__ wib, ushort* __restrict__ wob)
{
    const int b = blockIdx.x;
    const int tid = threadIdx.x;
    if (b < 512) {
        __shared__ unsigned int rb[8 * 1025];
        const int4* src = (const int4*)(mask + (size_t)b * 8 * 4096);
#pragma unroll
        for (int i = 0; i < 32; i++) {
            const int g = i * 256 + tid;
            int4 v = src[g];
            rb[(g >> 10) * 1025 + (g & 1023)] =
                ((unsigned int)(v.x & 15) << 4)  | ((unsigned int)(v.y & 15) << 12) |
                ((unsigned int)(v.z & 15) << 20) | ((unsigned int)(v.w & 15) << 28);
        }
        __syncthreads();
        const int t = b >> 1, half = b & 1;
#pragma unroll
        for (int i = 0; i < 32; i++) {
            const int dd = i * 256 + tid;
            const int nt = dd & 3, s = (dd >> 2) & 7, qd = (dd >> 5) & 3, kt = dd >> 7;
            const unsigned int w =
                rb[s * 1025 + kt * 16 + 8 * (nt >> 1) + 2 * qd + (nt & 1)];
            m2[(size_t)t * 16384 + kt * 256 + (qd * 16 + 8 * half + s) * 4 + nt] = w;
        }
    } else if (b < 1024) {
        const int t = (b - 512) * 256 + tid;
        ((bf16x8*)xb)[t] = cvt8(x + t * 8);
    } else if (b < 1120) {
        const int t = (b - 1024) * 256 + tid;
        ((bf16x8*)wib)[t] = cvt8(wi + t * 8);
    } else {
        const int t = (b - 1120) * 256 + tid;
        ((bf16x8*)wob)[t] = cvt8(wo + t * 8);
    }
}

// ---------------- Kernel 1: QKV projection (bf16 in, bf16 Q/K(sigma)/V^T out) ----------------
__global__ __launch_bounds__(256) void qkv_kernel(
        const ushort* __restrict__ xb, const ushort* __restrict__ wb,
        const float* __restrict__ b,
        ushort* __restrict__ Qb, ushort* __restrict__ Kb, ushort* __restrict__ Vt)
{
    const int lane = threadIdx.x & 63, wv = threadIdx.x >> 6;
    const int quad = lane >> 4, l15 = lane & 15;
    const int m0 = blockIdx.x * 64 + wv * 16;
    const int n0 = blockIdx.y * 64;

    f32x4 acc[4] = {};
    for (int ks = 0; ks < 8; ks++) {
        const int kd = ks * 32 + quad * 8;
        bf16x8 af = *(const bf16x8*)(xb + (m0 + l15) * D + kd);
#pragma unroll
        for (int nt = 0; nt < 4; nt++) {
            bf16x8 bfr = *(const bf16x8*)(wb + (n0 + nt * 16 + l15) * D + kd);
            acc[nt] = __builtin_amdgcn_mfma_f32_16x16x32_bf16(af, bfr, acc[nt], 0, 0, 0);
        }
    }
#pragma unroll
    for (int nt = 0; nt < 4; nt++) {
        const int j = n0 + nt * 16 + l15;
        const float bias = b[j];
#pragma unroll
        for (int r = 0; r < 4; r++) {
            const int row = m0 + quad * 4 + r;
            const float val = acc[nt][r] + bias;
            if (j < 256) {
                Qb[((j >> 5) * L + row) * DH + (j & 31)] = f2bf(val * RS);
            } else if (j < 512) {
                const int jj = j - 256;
                const int srow = (row & ~63) + ksig(row & 63);
                Kb[((jj >> 5) * L + srow) * DH + (jj & 31)] = f2bf(val);
            } else {
                const int jj = j - 512;
                Vt[((jj >> 5) * DH + (jj & 31)) * L + row] = f2bf(val);
            }
        }
    }
}

// ---------------- Kernel 2: register-resident flash attention ----------------
// S^T = K(sigma) Q^T; P in registers; conflict-free bias table; row-sums via ones-MFMA.
template<int KT>
__global__ __launch_bounds__(512) void attn_kernel(
        const ushort* __restrict__ Qb, const ushort* __restrict__ Kb,
        const ushort* __restrict__ Vt, const unsigned char* __restrict__ m2,
        const float* __restrict__ edge_bias,
        float* __restrict__ Opart, float* __restrict__ lpart)
{
    // [h][e][lane] fp32: ds addr/4 = h*1024 + e*64 + lane -> bank = lane%32 (2-way = free)
    __shared__ float ebt[8 * 16 * 64];

    const int tid = threadIdx.x;
    const int lane = tid & 63, h = tid >> 6;
    const int quad = lane >> 4, l15 = lane & 15;
    const int q0 = blockIdx.x * 16;
    const int ktbase = blockIdx.y * KT;

    {   // wave-private init of own head's slice
        float* t = ebt + h * 1024 + lane;
#pragma unroll
        for (int e = 0; e < 16; e++)
            t[e * 64] = (e < 14) ? edge_bias[e * H + h] * LOG2E : 0.f;
    }
    asm volatile("s_waitcnt lgkmcnt(0)" ::: "memory");   // one-time, wave-private

    const bf16x8 qf = *(const bf16x8*)(Qb + (h * L + q0 + l15) * DH + quad * 8);
    const char* ebl = (const char*)(ebt + h * 1024 + lane);   // + (maskbyte<<4)

    const ushort* Kp  = Kb + h * L * DH + ktbase * 64 * DH;
    const ushort* Vp0 = Vt + (h * DH + l15) * L + ktbase * 64;
    const ushort* Vp1 = Vt + (h * DH + 16 + l15) * L + ktbase * 64;
    const unsigned char* mp = m2 + (size_t)blockIdx.x * 65536
                            + (size_t)ktbase * 1024 + lane * 16;

    f32x4 o0 = {}, o1 = {}, osum = {};
    bf16x8 ones;
#pragma unroll
    for (int i = 0; i < 8; i++) ones[i] = (short)0x3F80;   // 1.0 bf16

#pragma unroll 2
    for (int kt = 0; kt < KT; kt++) {
        const int4 mw4 = *(const int4*)(mp + kt * 1024);
        const unsigned int mwa[4] = {(unsigned int)mw4.x, (unsigned int)mw4.y,
                                     (unsigned int)mw4.z, (unsigned int)mw4.w};

        // S^T = K(sigma-rows) Q^T
        f32x4 sv[4];
#pragma unroll
        for (int nt = 0; nt < 4; nt++) {
            bf16x8 kf = *(const bf16x8*)(Kp + (kt * 64 + nt * 16 + l15) * DH + quad * 8);
            f32x4 z = {};
            sv[nt] = __builtin_amdgcn_mfma_f32_16x16x32_bf16(kf, qf, z, 0, 0, 0);
        }

        bf16x8 v00 = *(const bf16x8*)(Vp0 + kt * 64 + quad * 8);
        bf16x8 v01 = *(const bf16x8*)(Vp1 + kt * 64 + quad * 8);
        bf16x8 v10 = *(const bf16x8*)(Vp0 + kt * 64 + 32 + quad * 8);
        bf16x8 v11 = *(const bf16x8*)(Vp1 + kt * 64 + 32 + quad * 8);

        // P^T = exp2(S^T + bias2[e]) — gather is conflict-free, offset = byte<<4
        float pv[16];
#pragma unroll
        for (int nt = 0; nt < 4; nt++) {
#pragma unroll
            for (int r = 0; r < 4; r++) {
                const unsigned int off = ((mwa[nt] >> (r * 8)) & 255u) << 4;
                const float b2 = *(const float*)(ebl + off);
                pv[nt * 4 + r] = __builtin_amdgcn_exp2f(sv[nt][r] + b2);
            }
        }

        // pack to PV B-fragments (native cvt_pk on gfx950)
        union { bf16x8 v; unsigned int u[4]; } pf0, pf1;
#pragma unroll
        for (int nt = 0; nt < 2; nt++) {
            pf0.u[nt * 2]     = pkbf(pv[nt * 4 + 0], pv[nt * 4 + 1]);
            pf0.u[nt * 2 + 1] = pkbf(pv[nt * 4 + 2], pv[nt * 4 + 3]);
            pf1.u[nt * 2]     = pkbf(pv[8 + nt * 4 + 0], pv[8 + nt * 4 + 1]);
            pf1.u[nt * 2 + 1] = pkbf(pv[8 + nt * 4 + 2], pv[8 + nt * 4 + 3]);
        }

        // O^T += V^T P^T ; row-sums on the MFMA pipe via ones-fragment
        o0   = __builtin_amdgcn_mfma_f32_16x16x32_bf16(v00, pf0.v, o0, 0, 0, 0);
        o1   = __builtin_amdgcn_mfma_f32_16x16x32_bf16(v01, pf0.v, o1, 0, 0, 0);
        osum = __builtin_amdgcn_mfma_f32_16x16x32_bf16(ones, pf0.v, osum, 0, 0, 0);
        o0   = __builtin_amdgcn_mfma_f32_16x16x32_bf16(v10, pf1.v, o0, 0, 0, 0);
        o1   = __builtin_amdgcn_mfma_f32_16x16x32_bf16(v11, pf1.v, o1, 0, 0, 0);
        osum = __builtin_amdgcn_mfma_f32_16x16x32_bf16(ones, pf1.v, osum, 0, 0, 0);
    }

    // osum rows are all identical (A=ones): osum[0] = full row-sum for q=l15. No shuffles.
    float* Op = Opart + (size_t)(blockIdx.y * 8 + h) * (L * 32) + (q0 + l15) * 32;
    float4 s0; s0.x = o0[0]; s0.y = o0[1]; s0.z = o0[2]; s0.w = o0[3];
    float4 s1; s1.x = o1[0]; s1.y = o1[1]; s1.z = o1[2]; s1.w = o1[3];
    *(float4*)(Op + quad * 4) = s0;
    *(float4*)(Op + 16 + quad * 4) = s1;
    if (quad == 0)
        lpart[(size_t)(blockIdx.y * 8 + h) * L + q0 + l15] = osum[0];
}

// ---------------- Kernel 2b: combine split partials -> AO bf16 ----------------
__global__ __launch_bounds__(256) void finalize_kernel(
        const float* __restrict__ Opart, const float* __restrict__ lpart,
        ushort* __restrict__ AO, int SP)
{
    const int t = blockIdx.x * 256 + threadIdx.x;
    const int q = t >> 8, c = t & 255;
    const int h = c >> 5, dh = c & 31;
    float o = 0.f, l = 0.f;
    for (int s = 0; s < SP; s++) {
        o += Opart[((size_t)(s * 8 + h) * L + q) * 32 + dh];
        l += lpart[(size_t)(s * 8 + h) * L + q];
    }
    AO[t] = f2bf(o / l);
}

// ---------------- Kernel 3: output projection (bf16 AO, bf16 W -> fp32 out) ----------------
__global__ __launch_bounds__(256) void oproj_kernel(
        const ushort* __restrict__ AO, const ushort* __restrict__ wb,
        const float* __restrict__ b, float* __restrict__ out)
{
    const int lane = threadIdx.x & 63, wv = threadIdx.x >> 6;
    const int quad = lane >> 4, l15 = lane & 15;
    const int m0 = blockIdx.x * 64 + wv * 16;
    const int n0 = blockIdx.y * 64;

    f32x4 acc[4] = {};
    for (int ks = 0; ks < 8; ks++) {
        const int kd = ks * 32 + quad * 8;
        bf16x8 af = *(const bf16x8*)(AO + (m0 + l15) * D + kd);
#pragma unroll
        for (int nt = 0; nt < 4; nt++) {
            bf16x8 bfr = *(const bf16x8*)(wb + (n0 + nt * 16 + l15) * D + kd);
            acc[nt] = __builtin_amdgcn_mfma_f32_16x16x32_bf16(af, bfr, acc[nt], 0, 0, 0);
        }
    }
#pragma unroll
    for (int nt = 0; nt < 4; nt++) {
        const int j = n0 + nt * 16 + l15;
        const float bias = b[j];
#pragma unroll
        for (int r = 0; r < 4; r++) {
            const int row = m0 + quad * 4 + r;
            out[row * D + j] = acc[nt][r] + bias;
        }
    }
}

extern "C" void kernel_launch(void* const* d_in, const int* in_sizes, int n_in,
                              void* d_out, int out_size, void* d_ws, size_t ws_size,
                              hipStream_t stream) {
    const float* x     = (const float*)d_in[0];
    const int*   mask  = (const int*)d_in[1];
    const float* in_w  = (const float*)d_in[2];
    const float* in_b  = (const float*)d_in[3];
    const float* out_w = (const float*)d_in[4];
    const float* out_b = (const float*)d_in[5];
    const float* eb    = (const float*)d_in[6];

    ushort* ws = (ushort*)d_ws;
    ushort* Qb  = ws;
    ushort* Kb  = Qb + H * L * DH;             // sigma-permuted rows
    ushort* Vt  = Kb + H * L * DH;
    ushort* xb  = Vt + H * L * DH;             // x bf16; reused as AO after attn
    ushort* wib = xb + L * D;
    ushort* wob = wib + 3 * D * D;
    unsigned char* m2 = (unsigned char*)(wob + D * D);           // 16 MB e<<4 stream
    float* Opart = (float*)(m2 + (size_t)L * L);
    int SP = (ws_size >= (size_t)25690112 + 4u * 4325376u) ? 4
           : (ws_size >= (size_t)25690112 + 2u * 4325376u) ? 2 : 1;
    float* lpart = Opart + (size_t)SP * H * L * DH;
    ushort* AO = xb;
    float* out = (float*)d_out;

    pack_kernel<<<dim3(1152), 256, 0, stream>>>(mask, x, in_w, out_w,
                                                (unsigned int*)m2, xb, wib, wob);
    qkv_kernel<<<dim3(64, 12), 256, 0, stream>>>(xb, wib, in_b, Qb, Kb, Vt);
    if (SP == 4)
        attn_kernel<16><<<dim3(256, 4), 512, 0, stream>>>(Qb, Kb, Vt, m2, eb, Opart, lpart);
    else if (SP == 2)
        attn_kernel<32><<<dim3(256, 2), 512, 0, stream>>>(Qb, Kb, Vt, m2, eb, Opart, lpart);
    else
        attn_kernel<64><<<dim3(256, 1), 512, 0, stream>>>(Qb, Kb, Vt, m2, eb, Opart, lpart);
    finalize_kernel<<<dim3(4096), 256, 0, stream>>>(Opart, lpart, AO, SP);
    oproj_kernel<<<dim3(64, 4), 256, 0, stream>>>(AO, wob, out_b, out);
}

// Round 9
// 230.390 us; speedup vs baseline: 1.0058x; 1.0058x over previous
//
#include <hip/hip_runtime.h>
#include <hip/hip_bf16.h>
#include <string.h>

#define L 4096
#define D 256
#define H 8
#define DH 32

typedef __attribute__((ext_vector_type(8))) short bf16x8;
typedef __attribute__((ext_vector_type(4))) float f32x4;

#define LOG2E 1.4426950408889634f
#define RS (0.17677669529663688f * LOG2E)   // 1/sqrt(DH) * log2(e), folded into Q

__device__ __forceinline__ ushort f2bf(float f) {
    union { float f; unsigned int i; } v; v.f = f;
    unsigned int x = v.i;
    return (ushort)((x + 0x7fffu + ((x >> 16) & 1u)) >> 16);   // RNE
}
__device__ __forceinline__ bf16x8 cvt8(const float* p) {
    float4 a = *(const float4*)p;
    float4 b = *(const float4*)(p + 4);
    bf16x8 r;
    r[0] = (short)f2bf(a.x); r[1] = (short)f2bf(a.y);
    r[2] = (short)f2bf(a.z); r[3] = (short)f2bf(a.w);
    r[4] = (short)f2bf(b.x); r[5] = (short)f2bf(b.y);
    r[6] = (short)f2bf(b.z); r[7] = (short)f2bf(b.w);
    return r;
}
// pack two fp32 -> bf16x2 dword; native v_cvt_pk_bf16_f32 on gfx950
__device__ __forceinline__ unsigned int pkbf(float a, float b) {
    float2 t; t.x = a; t.y = b;
    __hip_bfloat162 r = __float22bfloat162_rn(t);
    unsigned int u; memcpy(&u, &r, 4);
    return u;
}

// sigma: logical key u (0..63) -> K storage row within its 64-block.
__device__ __forceinline__ int ksig(int u) {
    return 32 * (u >> 5) + 16 * ((u >> 2) & 1) + 4 * ((u >> 3) & 3) + (u & 3);
}

// ---------------- Kernel 0: prepack ----------------
__global__ __launch_bounds__(256) void pack_kernel(
        const int* __restrict__ mask, const float* __restrict__ x,
        const float* __restrict__ wi, const float* __restrict__ wo,
        unsigned int* __restrict__ m2, ushort* __restrict__ xb,
        ushort* __restrict__ wib, ushort* __restrict__ wob)
{
    const int b = blockIdx.x;
    const int tid = threadIdx.x;
    if (b < 512) {
        __shared__ unsigned int rb[8 * 1025];
        const int4* src = (const int4*)(mask + (size_t)b * 8 * 4096);
#pragma unroll
        for (int i = 0; i < 32; i++) {
            const int g = i * 256 + tid;
            int4 v = src[g];
            rb[(g >> 10) * 1025 + (g & 1023)] =
                ((unsigned int)(v.x & 15) << 4)  | ((unsigned int)(v.y & 15) << 12) |
                ((unsigned int)(v.z & 15) << 20) | ((unsigned int)(v.w & 15) << 28);
        }
        __syncthreads();
        const int t = b >> 1, half = b & 1;
#pragma unroll
        for (int i = 0; i < 32; i++) {
            const int dd = i * 256 + tid;
            const int nt = dd & 3, s = (dd >> 2) & 7, qd = (dd >> 5) & 3, kt = dd >> 7;
            const unsigned int w =
                rb[s * 1025 + kt * 16 + 8 * (nt >> 1) + 2 * qd + (nt & 1)];
            m2[(size_t)t * 16384 + kt * 256 + (qd * 16 + 8 * half + s) * 4 + nt] = w;
        }
    } else if (b < 1024) {
        const int t = (b - 512) * 256 + tid;
        ((bf16x8*)xb)[t] = cvt8(x + t * 8);
    } else if (b < 1120) {
        const int t = (b - 1024) * 256 + tid;
        ((bf16x8*)wib)[t] = cvt8(wi + t * 8);
    } else {
        const int t = (b - 1120) * 256 + tid;
        ((bf16x8*)wob)[t] = cvt8(wo + t * 8);
    }
}

// ---------------- Kernel 1: QKV projection ----------------
__global__ __launch_bounds__(256) void qkv_kernel(
        const ushort* __restrict__ xb, const ushort* __restrict__ wb,
        const float* __restrict__ b,
        ushort* __restrict__ Qb, ushort* __restrict__ Kb, ushort* __restrict__ Vt)
{
    const int lane = threadIdx.x & 63, wv = threadIdx.x >> 6;
    const int quad = lane >> 4, l15 = lane & 15;
    const int m0 = blockIdx.x * 64 + wv * 16;
    const int n0 = blockIdx.y * 64;

    f32x4 acc[4] = {};
    for (int ks = 0; ks < 8; ks++) {
        const int kd = ks * 32 + quad * 8;
        bf16x8 af = *(const bf16x8*)(xb + (m0 + l15) * D + kd);
#pragma unroll
        for (int nt = 0; nt < 4; nt++) {
            bf16x8 bfr = *(const bf16x8*)(wb + (n0 + nt * 16 + l15) * D + kd);
            acc[nt] = __builtin_amdgcn_mfma_f32_16x16x32_bf16(af, bfr, acc[nt], 0, 0, 0);
        }
    }
#pragma unroll
    for (int nt = 0; nt < 4; nt++) {
        const int j = n0 + nt * 16 + l15;
        const float bias = b[j];
#pragma unroll
        for (int r = 0; r < 4; r++) {
            const int row = m0 + quad * 4 + r;
            const float val = acc[nt][r] + bias;
            if (j < 256) {
                Qb[((j >> 5) * L + row) * DH + (j & 31)] = f2bf(val * RS);
            } else if (j < 512) {
                const int jj = j - 256;
                const int srow = (row & ~63) + ksig(row & 63);
                Kb[((jj >> 5) * L + srow) * DH + (jj & 31)] = f2bf(val);
            } else {
                const int jj = j - 512;
                Vt[((jj >> 5) * DH + (jj & 31)) * L + row] = f2bf(val);
            }
        }
    }
}

// ---------------- Kernel 2: register-resident flash attention ----------------
// Fused per-half pipeline to minimize live VGPR+AGPR (occupancy was register-capped
// at ~3 waves/SIMD in R8: unified-file AGPRs don't show in VGPR_Count).
template<int KT>
__global__ __launch_bounds__(512) void attn_kernel(
        const ushort* __restrict__ Qb, const ushort* __restrict__ Kb,
        const ushort* __restrict__ Vt, const unsigned char* __restrict__ m2,
        const float* __restrict__ edge_bias,
        float* __restrict__ Opart, float* __restrict__ lpart)
{
    __shared__ float ebt[8 * 16 * 64];   // [h][e][lane] -> bank=lane%32, 2-way free

    const int tid = threadIdx.x;
    const int lane = tid & 63, h = tid >> 6;
    const int quad = lane >> 4, l15 = lane & 15;
    const int q0 = blockIdx.x * 16;
    const int ktbase = blockIdx.y * KT;

    {
        float* t = ebt + h * 1024 + lane;
#pragma unroll
        for (int e = 0; e < 16; e++)
            t[e * 64] = (e < 14) ? edge_bias[e * H + h] * LOG2E : 0.f;
    }
    asm volatile("s_waitcnt lgkmcnt(0)" ::: "memory");   // one-time, wave-private

    const bf16x8 qf = *(const bf16x8*)(Qb + (h * L + q0 + l15) * DH + quad * 8);
    const char* ebl = (const char*)(ebt + h * 1024 + lane);

    const ushort* Kp  = Kb + h * L * DH + ktbase * 64 * DH;
    const ushort* Vp0 = Vt + (h * DH + l15) * L + ktbase * 64;
    const ushort* Vp1 = Vt + (h * DH + 16 + l15) * L + ktbase * 64;
    const unsigned char* mp = m2 + (size_t)blockIdx.x * 65536
                            + (size_t)ktbase * 1024 + lane * 16;

    f32x4 o0 = {}, o1 = {}, osum = {};
    bf16x8 ones;
#pragma unroll
    for (int i = 0; i < 8; i++) ones[i] = (short)0x3F80;   // 1.0 bf16

    int4 mw = *(const int4*)mp;          // depth-1 mask prefetch

    for (int kt = 0; kt < KT; kt++) {
        const int4 mw_n = *(const int4*)(mp + (kt + 1) * 1024);  // next iter (ws-safe)
        const unsigned int mwa[4] = {(unsigned int)mw.x, (unsigned int)mw.y,
                                     (unsigned int)mw.z, (unsigned int)mw.w};

#pragma unroll
        for (int half = 0; half < 2; half++) {
            union { bf16x8 v; unsigned int u[4]; } pf;
#pragma unroll
            for (int nt2 = 0; nt2 < 2; nt2++) {
                const int nt = half * 2 + nt2;
                bf16x8 kf = *(const bf16x8*)(Kp + (kt * 64 + nt * 16 + l15) * DH + quad * 8);
                f32x4 z = {};
                f32x4 sv = __builtin_amdgcn_mfma_f32_16x16x32_bf16(kf, qf, z, 0, 0, 0);
                float p0, p1, p2, p3;
                {
                    const unsigned int w = mwa[nt];
                    p0 = __builtin_amdgcn_exp2f(sv[0] + *(const float*)(ebl + ((w       & 255u) << 4)));
                    p1 = __builtin_amdgcn_exp2f(sv[1] + *(const float*)(ebl + (((w >> 8)  & 255u) << 4)));
                    p2 = __builtin_amdgcn_exp2f(sv[2] + *(const float*)(ebl + (((w >> 16) & 255u) << 4)));
                    p3 = __builtin_amdgcn_exp2f(sv[3] + *(const float*)(ebl + ((w >> 24)        << 4)));
                }
                pf.u[nt2 * 2]     = pkbf(p0, p1);
                pf.u[nt2 * 2 + 1] = pkbf(p2, p3);
            }
            bf16x8 va = *(const bf16x8*)(Vp0 + kt * 64 + half * 32 + quad * 8);
            bf16x8 vb = *(const bf16x8*)(Vp1 + kt * 64 + half * 32 + quad * 8);
            o0   = __builtin_amdgcn_mfma_f32_16x16x32_bf16(va, pf.v, o0, 0, 0, 0);
            o1   = __builtin_amdgcn_mfma_f32_16x16x32_bf16(vb, pf.v, o1, 0, 0, 0);
            osum = __builtin_amdgcn_mfma_f32_16x16x32_bf16(ones, pf.v, osum, 0, 0, 0);
        }
        mw = mw_n;
    }

    float* Op = Opart + (size_t)(blockIdx.y * 8 + h) * (L * 32) + (q0 + l15) * 32;
    float4 s0; s0.x = o0[0]; s0.y = o0[1]; s0.z = o0[2]; s0.w = o0[3];
    float4 s1; s1.x = o1[0]; s1.y = o1[1]; s1.z = o1[2]; s1.w = o1[3];
    *(float4*)(Op + quad * 4) = s0;
    *(float4*)(Op + 16 + quad * 4) = s1;
    if (quad == 0)
        lpart[(size_t)(blockIdx.y * 8 + h) * L + q0 + l15] = osum[0];
}

// ---------------- Kernel 2b: combine split partials -> AO bf16 ----------------
__global__ __launch_bounds__(256) void finalize_kernel(
        const float* __restrict__ Opart, const float* __restrict__ lpart,
        ushort* __restrict__ AO, int SP)
{
    const int t = blockIdx.x * 256 + threadIdx.x;
    const int q = t >> 8, c = t & 255;
    const int h = c >> 5, dh = c & 31;
    float o = 0.f, l = 0.f;
    for (int s = 0; s < SP; s++) {
        o += Opart[((size_t)(s * 8 + h) * L + q) * 32 + dh];
        l += lpart[(size_t)(s * 8 + h) * L + q];
    }
    AO[t] = f2bf(o / l);
}

// ---------------- Kernel 3: output projection ----------------
__global__ __launch_bounds__(256) void oproj_kernel(
        const ushort* __restrict__ AO, const ushort* __restrict__ wb,
        const float* __restrict__ b, float* __restrict__ out)
{
    const int lane = threadIdx.x & 63, wv = threadIdx.x >> 6;
    const int quad = lane >> 4, l15 = lane & 15;
    const int m0 = blockIdx.x * 64 + wv * 16;
    const int n0 = blockIdx.y * 64;

    f32x4 acc[4] = {};
    for (int ks = 0; ks < 8; ks++) {
        const int kd = ks * 32 + quad * 8;
        bf16x8 af = *(const bf16x8*)(AO + (m0 + l15) * D + kd);
#pragma unroll
        for (int nt = 0; nt < 4; nt++) {
            bf16x8 bfr = *(const bf16x8*)(wb + (n0 + nt * 16 + l15) * D + kd);
            acc[nt] = __builtin_amdgcn_mfma_f32_16x16x32_bf16(af, bfr, acc[nt], 0, 0, 0);
        }
    }
#pragma unroll
    for (int nt = 0; nt < 4; nt++) {
        const int j = n0 + nt * 16 + l15;
        const float bias = b[j];
#pragma unroll
        for (int r = 0; r < 4; r++) {
            const int row = m0 + quad * 4 + r;
            out[row * D + j] = acc[nt][r] + bias;
        }
    }
}

extern "C" void kernel_launch(void* const* d_in, const int* in_sizes, int n_in,
                              void* d_out, int out_size, void* d_ws, size_t ws_size,
                              hipStream_t stream) {
    const float* x     = (const float*)d_in[0];
    const int*   mask  = (const int*)d_in[1];
    const float* in_w  = (const float*)d_in[2];
    const float* in_b  = (const float*)d_in[3];
    const float* out_w = (const float*)d_in[4];
    const float* out_b = (const float*)d_in[5];
    const float* eb    = (const float*)d_in[6];

    ushort* ws = (ushort*)d_ws;
    ushort* Qb  = ws;
    ushort* Kb  = Qb + H * L * DH;             // sigma-permuted rows
    ushort* Vt  = Kb + H * L * DH;
    ushort* xb  = Vt + H * L * DH;             // x bf16; reused as AO after attn
    ushort* wib = xb + L * D;
    ushort* wob = wib + 3 * D * D;
    unsigned char* m2 = (unsigned char*)(wob + D * D);           // 16 MB e<<4 stream
    float* Opart = (float*)(m2 + (size_t)L * L);
    int SP = (ws_size >= (size_t)25690112 + 4u * 4325376u) ? 4
           : (ws_size >= (size_t)25690112 + 2u * 4325376u) ? 2 : 1;
    float* lpart = Opart + (size_t)SP * H * L * DH;
    ushort* AO = xb;
    float* out = (float*)d_out;

    pack_kernel<<<dim3(1152), 256, 0, stream>>>(mask, x, in_w, out_w,
                                                (unsigned int*)m2, xb, wib, wob);
    qkv_kernel<<<dim3(64, 12), 256, 0, stream>>>(xb, wib, in_b, Qb, Kb, Vt);
    if (SP == 4)
        attn_kernel<16><<<dim3(256, 4), 512, 0, stream>>>(Qb, Kb, Vt, m2, eb, Opart, lpart);
    else if (SP == 2)
        attn_kernel<32><<<dim3(256, 2), 512, 0, stream>>>(Qb, Kb, Vt, m2, eb, Opart, lpart);
    else
        attn_kernel<64><<<dim3(256, 1), 512, 0, stream>>>(Qb, Kb, Vt, m2, eb, Opart, lpart);
    finalize_kernel<<<dim3(4096), 256, 0, stream>>>(Opart, lpart, AO, SP);
    oproj_kernel<<<dim3(64, 4), 256, 0, stream>>>(AO, wob, out_b, out);
}